// Round 1
// baseline (563.779 us; speedup 1.0000x reference)
//
#include <hip/hip_runtime.h>

#define BATCH 512
#define T 784
#define H 256
#define NROWS 16      // batch rows per block
#define NWAVES 4      // waves per block

typedef __attribute__((ext_vector_type(8))) short short8;
typedef __attribute__((ext_vector_type(4))) float f32x4;
typedef __attribute__((ext_vector_type(4))) unsigned short ushort4_t;

__device__ inline unsigned short f2bf(float f) {
  unsigned u = __builtin_bit_cast(unsigned, f);
  u += 0x7fffu + ((u >> 16) & 1u);           // RNE
  return (unsigned short)(u >> 16);
}
__device__ inline float bf2f(unsigned short s) {
  return __builtin_bit_cast(float, (unsigned)s << 16);
}

// One block = 16 batch rows, full 784-step recurrence in-block.
// Orientation: D[j, b] = sum_k W_hh[j,k] * h[b,k]
//   A (arg0) = W_hh tile rows (m = lane&15 -> j), constant in registers
//   B (arg1) = h rows        (n = lane&15 -> b), re-read from LDS per step
//   D: col = lane&15 = b, row = (lane>>4)*4 + q = j-within-tile  [m89 verified]
__global__ __launch_bounds__(256, 1)
void irnn_kernel(const float* __restrict__ x,   const float* __restrict__ Wih,
                 const float* __restrict__ bih, const float* __restrict__ Whh,
                 const float* __restrict__ bhh, const float* __restrict__ Wout,
                 const float* __restrict__ bout, float* __restrict__ out)
{
  // h double-buffer, bf16, XOR-swizzled on 16B slots: elem (b,j) at
  // ushort index b*256 + ((j/8)^(b&7))*8 + (j%8)
  __shared__ unsigned short hbuf[2][NROWS * H];
  __shared__ float logit_lds[NROWS][10];

  const int tid = threadIdx.x;
  const int w   = tid >> 6;      // wave 0..3 : j in [64w, 64w+64)
  const int l   = tid & 63;
  const int br  = l & 15;        // batch row within block (n), also m for A
  const int g   = l >> 4;        // k-group 0..3
  const int blk = blockIdx.x;

  // ---- stage A fragments: W_hh rows, bf16, registers (constant all steps) ----
  short8 a[4][8];                // [j-tile][k-slice]
  #pragma unroll
  for (int mt = 0; mt < 4; ++mt) {
    const int j = 64 * w + 16 * mt + br;
    #pragma unroll
    for (int c = 0; c < 8; ++c) {
      const int kb = 32 * c + 8 * g;
      const float* p = &Whh[j * H + kb];
      short8 af;
      #pragma unroll
      for (int e = 0; e < 8; ++e) af[e] = (short)f2bf(p[e]);
      a[mt][c] = af;
    }
  }

  // ---- per-lane epilogue constants: j = 64w + 16mt + 4g + q ----
  float wj[4][4], bj[4][4];
  #pragma unroll
  for (int mt = 0; mt < 4; ++mt)
    #pragma unroll
    for (int q = 0; q < 4; ++q) {
      const int j = 64 * w + 16 * mt + 4 * g + q;
      wj[mt][q] = Wih[j];              // W_ih is (H,1)
      bj[mt][q] = bih[j] + bhh[j];
    }

  // ---- h0 = 0 ----
  for (int i = tid; i < NROWS * H / 2; i += 256)
    reinterpret_cast<unsigned*>(hbuf[0])[i] = 0u;

  // ---- precomputed swizzled LDS offsets (ushort units) ----
  int rdo[8];                    // read: frag c -> h[br][32c+8g .. +8)
  #pragma unroll
  for (int c = 0; c < 8; ++c)
    rdo[c] = br * H + (((4 * c + g) ^ (br & 7)) << 3);
  int wro[4];                    // write: tile mt -> 4 bf16 at j0 = 64w+16mt+4g
  #pragma unroll
  for (int mt = 0; mt < 4; ++mt) {
    const int s = 8 * w + 2 * mt + (g >> 1);     // j0/8
    wro[mt] = br * H + ((s ^ (br & 7)) << 3) + (g & 1) * 4;
  }

  const float* xrow = &x[(blk * NROWS + br) * T];
  float xt = xrow[0];

  __syncthreads();

  for (int t = 0; t < T; ++t) {
    const unsigned short* rb = hbuf[t & 1];
    unsigned short*       wb = hbuf[(t & 1) ^ 1];

    short8 bfr[8];
    #pragma unroll
    for (int c = 0; c < 8; ++c)
      bfr[c] = *reinterpret_cast<const short8*>(&rb[rdo[c]]);

    const float xn = xrow[(t + 1 < T) ? t + 1 : t];   // prefetch next x_t (L2)

    f32x4 acc[4];
    #pragma unroll
    for (int mt = 0; mt < 4; ++mt) acc[mt] = f32x4{0.f, 0.f, 0.f, 0.f};
    #pragma unroll
    for (int c = 0; c < 8; ++c)          // interleave 4 independent chains
      #pragma unroll
      for (int mt = 0; mt < 4; ++mt)
        acc[mt] = __builtin_amdgcn_mfma_f32_16x16x32_bf16(a[mt][c], bfr[c], acc[mt], 0, 0, 0);

    #pragma unroll
    for (int mt = 0; mt < 4; ++mt) {
      ushort4_t hw;
      #pragma unroll
      for (int q = 0; q < 4; ++q) {
        float v = acc[mt][q] + xt * wj[mt][q] + bj[mt][q];
        v = fmaxf(v, 0.f);
        hw[q] = f2bf(v);
      }
      *reinterpret_cast<ushort4_t*>(&wb[wro[mt]]) = hw;   // ds_write_b64
    }
    xt = xn;
    __syncthreads();
  }

  // ---- final h is in hbuf[0] (784 even). logits + log_softmax ----
  if (tid < NROWS * 10) {
    const int tb = tid / 10, tc = tid % 10;
    float s = bout[tc];
    for (int j = 0; j < H; ++j) {
      const int idx = tb * H + ((((j >> 3) ^ (tb & 7)) << 3) | (j & 7));
      s += bf2f(hbuf[0][idx]) * Wout[tc * H + j];
    }
    logit_lds[tb][tc] = s;
  }
  __syncthreads();
  if (tid < NROWS * 10) {
    const int tb = tid / 10, tc = tid % 10;
    float m = logit_lds[tb][0];
    #pragma unroll
    for (int c = 1; c < 10; ++c) m = fmaxf(m, logit_lds[tb][c]);
    float sum = 0.f;
    #pragma unroll
    for (int c = 0; c < 10; ++c) sum += expf(logit_lds[tb][c] - m);
    out[(blk * NROWS + tb) * 10 + tc] = logit_lds[tb][tc] - m - logf(sum);
  }
}

extern "C" void kernel_launch(void* const* d_in, const int* in_sizes, int n_in,
                              void* d_out, int out_size, void* d_ws, size_t ws_size,
                              hipStream_t stream) {
  const float* x    = (const float*)d_in[0];
  const float* Wih  = (const float*)d_in[1];
  const float* bih  = (const float*)d_in[2];
  const float* Whh  = (const float*)d_in[3];
  const float* bhh  = (const float*)d_in[4];
  const float* Wout = (const float*)d_in[5];
  const float* bout = (const float*)d_in[6];
  irnn_kernel<<<BATCH / NROWS, 256, 0, stream>>>(x, Wih, bih, Whh, bhh, Wout, bout,
                                                 (float*)d_out);
}